// Round 2
// baseline (173.608 us; speedup 1.0000x reference)
//
#include <hip/hip_runtime.h>

// GetInitialSymbol: structured single-head cross-attention + residual.
// SLICES = (d_in=512, w_pos=32, st=0, sym1=8, sym2=40, pos1=72, pos2=104,
//           pos3=136, scr1=168, scr2=200, scr3=232, scr4=264, scr5=296)
//   q_i = 2*tgt[136+i]-1 (i<32), q_32 = 1          (w_q rows @ pos3_)
//   k_i = 2*mem[72+i]-1  (i<32), k_32 = 0          (w_k rows @ pos1_)
//   v_{200+j} = mem[8+j] (j<32), v_265 = 1         (w_v: scr2_ rows, sym1_ cols; b_v[scr4_+1])
//   fixed token: score = q_32 * 31 = 31, value = 0
#define B_   8
#define T_   2048
#define S_   2048
#define DIN  512
#define QOFF 136
#define KOFF 72
#define VSRC 8

constexpr int ROWS   = 64;          // t-rows per block (lane == row)
constexpr int NW     = 16;          // waves per block (S-chunks)
constexpr int BLK    = ROWS * NW;   // 1024 threads
constexpr int SCHUNK = S_ / NW;     // 128 keys per wave
constexpr int U      = 8;           // keys per rescale sub-chunk

__device__ __forceinline__ void merge_write(float* lds, int slot, int lane,
                                            float m, float ls, const float* acc) {
  float* dst = lds + slot * (34 * 64);
  dst[lane]      = m;
  dst[64 + lane] = ls;
  #pragma unroll
  for (int i = 0; i < 32; ++i) dst[(2 + i) * 64 + lane] = acc[i];
}

__device__ __forceinline__ void merge_read(const float* lds, int slot, int lane,
                                           float& m, float& ls, float* acc) {
  const float* src = lds + slot * (34 * 64);
  float m2 = src[lane];
  float l2 = src[64 + lane];
  float mn = fmaxf(m, m2);
  float sa = __expf(m - mn);
  float sb = __expf(m2 - mn);
  ls = ls * sa + l2 * sb;
  #pragma unroll
  for (int i = 0; i < 32; ++i)
    acc[i] = acc[i] * sa + src[(2 + i) * 64 + lane] * sb;
  m = mn;
}

__global__ __launch_bounds__(BLK)
void attn_fused(const float* __restrict__ tgt, const float* __restrict__ mem,
                float* __restrict__ out) {
  // 4 merge slots of (m, l, acc[32]) x 64 lanes = 34816 B; reused for results.
  __shared__ float lds[4 * 34 * 64];

  const int tid  = threadIdx.x;
  const int lane = tid & 63;
  const int wv   = tid >> 6;
  const int b    = blockIdx.x >> 5;          // T_/ROWS = 32 row-groups per batch
  const int t0   = (blockIdx.x & 31) * ROWS;
  const int row  = t0 + lane;

  // Per-lane q: p[i] = 4*tgt-2 (folded 2x), qs = sum(2*tgt-1).
  // score(s) = sum_i mem_s[KOFF+i]*p[i] - qs   since (2t-1)(2m-1)=m(4t-2)-(2t-1)
  const float* trow = tgt + ((size_t)(b * T_ + row)) * DIN;
  float p[32];
  float qs = 0.f;
  #pragma unroll
  for (int i8 = 0; i8 < 8; ++i8) {
    float4 tq = *(const float4*)(trow + QOFF + i8 * 4);
    float q0 = 2.f * tq.x - 1.f, q1 = 2.f * tq.y - 1.f;
    float q2 = 2.f * tq.z - 1.f, q3 = 2.f * tq.w - 1.f;
    p[i8 * 4 + 0] = 2.f * q0; p[i8 * 4 + 1] = 2.f * q1;
    p[i8 * 4 + 2] = 2.f * q2; p[i8 * 4 + 3] = 2.f * q3;
    qs += q0 + q1 + q2 + q3;
  }

  // Online softmax state; fixed token (score 31, v=0) seeded in wave 0 only.
  float m  = (wv == 0) ? 31.f : -3.0e38f;
  float ls = (wv == 0) ? 1.f : 0.f;
  float acc[32];
  #pragma unroll
  for (int i = 0; i < 32; ++i) acc[i] = 0.f;

  const float* mb = mem + (size_t)b * S_ * DIN;
  const int s0 = __builtin_amdgcn_readfirstlane(wv * SCHUNK);  // wave-uniform

  for (int s = s0; s < s0 + SCHUNK; s += U) {
    float sc[U];
    #pragma unroll
    for (int u = 0; u < U; ++u) {
      const float* kr = mb + (size_t)(s + u) * DIN + KOFF;  // uniform -> s_load
      float d = -qs;
      #pragma unroll
      for (int i = 0; i < 32; ++i) d = fmaf(kr[i], p[i], d);
      sc[u] = d;
    }
    float cm = sc[0];
    #pragma unroll
    for (int u = 1; u < U; ++u) cm = fmaxf(cm, sc[u]);
    const float mn = fmaxf(m, cm);
    const float scale = __expf(m - mn);   // exp(-huge) -> 0 on first chunk
    m = mn;
    ls *= scale;
    #pragma unroll
    for (int i = 0; i < 32; ++i) acc[i] *= scale;
    #pragma unroll
    for (int u = 0; u < U; ++u) {
      const float pe = __expf(sc[u] - m);
      ls += pe;
      const float* vr = mb + (size_t)(s + u) * DIN + VSRC;  // uniform -> s_load
      #pragma unroll
      for (int i = 0; i < 32; ++i) acc[i] = fmaf(pe, vr[i], acc[i]);
    }
  }

  // Tree-merge 16 wave partials -> wave 0, max 4 LDS slots in flight.
  #define ROUND(WLO, WHI, MLO)                                                  \
    if (wv >= (WLO) && wv <= (WHI)) merge_write(lds, wv - (WLO), lane, m, ls, acc); \
    __syncthreads();                                                            \
    if (wv >= (MLO) && wv <= (MLO) + ((WHI) - (WLO)))                           \
      merge_read(lds, wv - (MLO), lane, m, ls, acc);                            \
    __syncthreads();
  ROUND(8, 11, 0)
  ROUND(12, 15, 4)
  ROUND(4, 7, 0)
  ROUND(2, 3, 0)
  ROUND(1, 1, 0)
  #undef ROUND

  // Wave 0 publishes normalized results: res[j][row] j=0..31 (channels 200..231),
  // res[32][row] = delta for channel 265 = 1 - attn_weight(fixed token).
  if (wv == 0) {
    const float inv = 1.f / ls;
    #pragma unroll
    for (int i = 0; i < 32; ++i) lds[i * 64 + lane] = acc[i] * inv;
    lds[32 * 64 + lane] = 1.f - __expf(31.f - m) * inv;
  }
  __syncthreads();

  // Epilogue: out = tgt + sparse update. 64 rows x 128 float4 = 8192; 8/thread.
  const size_t base = ((size_t)(b * T_ + t0)) * DIN;
  #pragma unroll
  for (int k = 0; k < 8; ++k) {
    const int vid = tid + k * BLK;
    const int r   = vid >> 7;     // float4-row (128 float4 per row)
    const int c4  = vid & 127;
    const size_t off = base + (size_t)r * DIN + c4 * 4;
    float4 ov = *(const float4*)(tgt + off);
    if (c4 >= 50 && c4 < 58) {            // channels 200..231
      const int j = (c4 - 50) * 4;
      ov.x += lds[(j + 0) * 64 + r];
      ov.y += lds[(j + 1) * 64 + r];
      ov.z += lds[(j + 2) * 64 + r];
      ov.w += lds[(j + 3) * 64 + r];
    } else if (c4 == 66) {                // channel 265 is .y of float4 66
      ov.y += lds[32 * 64 + r];
    }
    *(float4*)(out + off) = ov;
  }
}

extern "C" void kernel_launch(void* const* d_in, const int* in_sizes, int n_in,
                              void* d_out, int out_size, void* d_ws, size_t ws_size,
                              hipStream_t stream) {
  const float* tgt = (const float*)d_in[0];
  const float* mem = (const float*)d_in[1];
  float* out = (float*)d_out;
  attn_fused<<<dim3(B_ * (T_ / ROWS)), dim3(BLK), 0, stream>>>(tgt, mem, out);
}

// Round 3
// 92.514 us; speedup vs baseline: 1.8766x; 1.8766x over previous
//
#include <hip/hip_runtime.h>

// GetInitialSymbol: structured single-head cross-attention + residual.
// SLICES = (d_in=512, w_pos=32, st=0, sym1=8, sym2=40, pos1=72, pos2=104,
//           pos3=136, scr1=168, scr2=200, scr3=232, scr4=264, scr5=296)
//   q_i = 2*tgt[136+i]-1 (i<32), q_32 = 1
//   k_i = 2*mem[72+i]-1  (i<32), k_32 = 0
//   v_{200+j} = mem[8+j] (j<32), v_265 = 1
//   fixed token: score = 31, value = 0
#define B_   8
#define T_   2048
#define S_   2048
#define DIN  512
#define QOFF 136
#define KOFF 72
#define VSRC 8

constexpr int ROWS  = 64;           // t-rows per block (lane == row)
constexpr int NW    = 16;           // waves per block (S-chunks)
constexpr int BLK   = ROWS * NW;    // 1024 threads
constexpr int WKEYS = S_ / NW;      // 128 keys per wave
constexpr int CK    = 8;            // keys per staged chunk
constexpr int NCH   = WKEYS / CK;   // 16 chunks per wave
// Per-wave staging: 2 bufs x CK keys x 64 floats (32 K + 32 V) = 1024 floats.
constexpr int WLDS  = 2 * CK * 64;  // 1024 floats / wave

__device__ __forceinline__ void merge_write(float* sh, int slot, int lane,
                                            float m, float ls, const float* acc) {
  float* dst = sh + slot * (34 * 64);
  dst[lane]      = m;
  dst[64 + lane] = ls;
  #pragma unroll
  for (int i = 0; i < 32; ++i) dst[(2 + i) * 64 + lane] = acc[i];
}

__device__ __forceinline__ void merge_read(const float* sh, int slot, int lane,
                                           float& m, float& ls, float* acc) {
  const float* src = sh + slot * (34 * 64);
  float m2 = src[lane];
  float l2 = src[64 + lane];
  float mn = fmaxf(m, m2);
  float sa = __expf(m - mn);
  float sb = __expf(m2 - mn);
  ls = ls * sa + l2 * sb;
  #pragma unroll
  for (int i = 0; i < 32; ++i)
    acc[i] = acc[i] * sa + src[(2 + i) * 64 + lane] * sb;
  m = mn;
}

// Stage CK=8 keys' K-slice+V-slice into wave-private LDS with 2 direct-to-LDS
// loads (no VGPR/SGPR round-trip). Lane i covers key (j*4 + i>>4), 16B part i&15:
// parts 0..7 = K floats [72,104), parts 8..15 = V floats [8,40).
__device__ __forceinline__ void stage_chunk(const float* mb, int key0, float* dst) {
  const int lane = threadIdx.x & 63;
  const int pp   = lane & 15;
  const int foff = (pp < 8) ? (KOFF + 4 * pp) : (VSRC + 4 * (pp - 8));
  #pragma unroll
  for (int j = 0; j < 2; ++j) {
    const float* g = mb + (size_t)(key0 + j * 4 + (lane >> 4)) * DIN + foff;
    __builtin_amdgcn_global_load_lds(
        (const __attribute__((address_space(1))) void*)g,
        (__attribute__((address_space(3))) void*)(dst + j * 256), 16, 0, 0);
  }
}

__global__ __launch_bounds__(BLK)
void attn_fused(const float* __restrict__ tgt, const float* __restrict__ mem,
                float* __restrict__ out) {
  // 64 KB: staging (16 waves x 1024 floats). Merge slots (4 x 34 x 64 = 8704
  // floats) and result block (33 x 64) overlay the staging region afterwards.
  __shared__ float sh[NW * WLDS];

  const int tid  = threadIdx.x;
  const int lane = tid & 63;
  const int wv   = tid >> 6;
  const int b    = blockIdx.x >> 5;          // 32 row-groups per batch
  const int t0   = (blockIdx.x & 31) * ROWS;
  const int row  = t0 + lane;

  // Per-lane q: p[i] = 4*tgt-2, qs = sum(2*tgt-1).
  // score(s) = sum_i mem_s[KOFF+i]*p[i] - qs
  const float* trow = tgt + ((size_t)(b * T_ + row)) * DIN;
  float p[32];
  float qs = 0.f;
  #pragma unroll
  for (int i8 = 0; i8 < 8; ++i8) {
    float4 tq = *(const float4*)(trow + QOFF + i8 * 4);
    float q0 = 2.f * tq.x - 1.f, q1 = 2.f * tq.y - 1.f;
    float q2 = 2.f * tq.z - 1.f, q3 = 2.f * tq.w - 1.f;
    p[i8 * 4 + 0] = 2.f * q0; p[i8 * 4 + 1] = 2.f * q1;
    p[i8 * 4 + 2] = 2.f * q2; p[i8 * 4 + 3] = 2.f * q3;
    qs += q0 + q1 + q2 + q3;
  }

  // Online softmax state; fixed token (score 31, v=0) seeded in wave 0 only.
  float m  = (wv == 0) ? 31.f : -3.0e38f;
  float ls = (wv == 0) ? 1.f : 0.f;
  float acc[32];
  #pragma unroll
  for (int i = 0; i < 32; ++i) acc[i] = 0.f;

  const float* mb   = mem + (size_t)b * S_ * DIN;
  float* mybuf      = sh + wv * WLDS;
  const int wkey0   = wv * WKEYS;

  stage_chunk(mb, wkey0, mybuf);             // prologue: chunk 0 -> buf 0

  for (int c = 0; c < NCH; ++c) {
    if (c + 1 < NCH) {
      stage_chunk(mb, wkey0 + (c + 1) * CK, mybuf + ((c + 1) & 1) * 512);
      asm volatile("s_waitcnt vmcnt(2)" ::: "memory");   // chunk c complete
    } else {
      asm volatile("s_waitcnt vmcnt(0)" ::: "memory");
    }
    const float* buf = mybuf + (c & 1) * 512;

    float sc[CK];
    #pragma unroll
    for (int u = 0; u < CK; ++u) {
      const float* kb = buf + u * 64;        // uniform -> ds_read_b128 broadcast
      float d = -qs;
      #pragma unroll
      for (int i = 0; i < 32; ++i) d = fmaf(kb[i], p[i], d);
      sc[u] = d;
    }
    float cm = sc[0];
    #pragma unroll
    for (int u = 1; u < CK; ++u) cm = fmaxf(cm, sc[u]);
    if (__any(cm > m)) {                     // defer-rescale: skip if max static
      const float mn = fmaxf(m, cm);
      const float scale = __expf(m - mn);    // exp(-huge) -> 0 on first chunk
      m = mn;
      ls *= scale;
      #pragma unroll
      for (int i = 0; i < 32; ++i) acc[i] *= scale;
    }
    #pragma unroll
    for (int u = 0; u < CK; ++u) {
      const float pe = __expf(sc[u] - m);
      ls += pe;
      const float* vb = buf + u * 64 + 32;
      #pragma unroll
      for (int i = 0; i < 32; ++i) acc[i] = fmaf(pe, vb[i], acc[i]);
    }
    asm volatile("" ::: "memory");
  }

  __syncthreads();   // staging region now retired; merge slots overlay it

  // Tree-merge 16 wave partials -> wave 0, max 4 LDS slots in flight.
  #define ROUND(WLO, WHI, MLO)                                                  \
    if (wv >= (WLO) && wv <= (WHI)) merge_write(sh, wv - (WLO), lane, m, ls, acc); \
    __syncthreads();                                                            \
    if (wv >= (MLO) && wv <= (MLO) + ((WHI) - (WLO)))                           \
      merge_read(sh, wv - (MLO), lane, m, ls, acc);                             \
    __syncthreads();
  ROUND(8, 11, 0)
  ROUND(12, 15, 4)
  ROUND(4, 7, 0)
  ROUND(2, 3, 0)
  ROUND(1, 1, 0)
  #undef ROUND

  // Wave 0 publishes normalized results: res[j][row] j=0..31 (channels 200..231),
  // res[32][row] = delta for channel 265 = 1 - attn_weight(fixed token).
  if (wv == 0) {
    const float inv = 1.f / ls;
    #pragma unroll
    for (int i = 0; i < 32; ++i) sh[i * 64 + lane] = acc[i] * inv;
    sh[32 * 64 + lane] = 1.f - __expf(31.f - m) * inv;
  }
  __syncthreads();

  // Epilogue: out = tgt + sparse update. 64 rows x 128 float4 = 8192; 8/thread.
  const size_t base = ((size_t)(b * T_ + t0)) * DIN;
  #pragma unroll
  for (int k = 0; k < 8; ++k) {
    const int vid = tid + k * BLK;
    const int r   = vid >> 7;     // float4-row (128 float4 per row)
    const int c4  = vid & 127;
    const size_t off = base + (size_t)r * DIN + c4 * 4;
    float4 ov = *(const float4*)(tgt + off);
    if (c4 >= 50 && c4 < 58) {            // channels 200..231
      const int j = (c4 - 50) * 4;
      ov.x += sh[(j + 0) * 64 + r];
      ov.y += sh[(j + 1) * 64 + r];
      ov.z += sh[(j + 2) * 64 + r];
      ov.w += sh[(j + 3) * 64 + r];
    } else if (c4 == 66) {                // channel 265 is .y of float4 66
      ov.y += sh[32 * 64 + r];
    }
    *(float4*)(out + off) = ov;
  }
}

extern "C" void kernel_launch(void* const* d_in, const int* in_sizes, int n_in,
                              void* d_out, int out_size, void* d_ws, size_t ws_size,
                              hipStream_t stream) {
  const float* tgt = (const float*)d_in[0];
  const float* mem = (const float*)d_in[1];
  float* out = (float*)d_out;
  attn_fused<<<dim3(B_ * (T_ / ROWS)), dim3(BLK), 0, stream>>>(tgt, mem, out);
}

// Round 4
// 36.719 us; speedup vs baseline: 4.7280x; 2.5195x over previous
//
#include <hip/hip_runtime.h>
#include <hip/hip_bf16.h>

// GetInitialSymbol: structured single-head cross-attention + residual, MFMA version.
//   q_i = 2*tgt[136+i]-1 (i<32); k_i = 2*mem[72+i]-1; v_{200+j} = mem[8+j]; v_265 = 1
//   fixed token: score=31, value=0.
// Flash-attn D=32: scores = 3x mfma_16x16x32_bf16 (hi/lo split), PV = mfma with
// bf16 V/W. Swapped operands so lane&15 == q-row everywhere (C: col=lane&15).
#define B_   8
#define T_   2048
#define S_   2048
#define DIN  512
#define QOFF 136
#define KOFF 72
#define VSRC 8

typedef __attribute__((ext_vector_type(8))) short bf16x8;
typedef __attribute__((ext_vector_type(4))) float f32x4;

constexpr int BLK  = 512;        // 8 waves: rg = wv&3 (16-row tile), ks = wv>>2 (key seg)
constexpr int GK   = 64;         // keys per staged group
constexpr int SEG  = S_ / 2;     // 1024 keys per segment
constexpr int NG   = SEG / GK;   // 16 groups
constexpr int BUFU = 6400;       // ushorts per (ks,buf): Khi[64*32]@0, Klo@2048, Vt[32*72]@4096

__device__ __forceinline__ ushort f2b(float x) {
  __hip_bfloat16 h = __float2bfloat16(x);
  return __builtin_bit_cast(ushort, h);
}
__device__ __forceinline__ float b2f(ushort s) {
  return __bfloat162float(__builtin_bit_cast(__hip_bfloat16, s));
}

struct Stage { float4 k4[2]; float v[8]; };

// cohort (4 waves, 256 lanes) stages GK=64 keys: K rows 72..103 (hi/lo bf16) and
// V^T (ch x key) with the PV-fragment column permutation baked into addresses.
__device__ __forceinline__ void stage_issue(const float* __restrict__ mb, int key0,
                                            int ct, Stage& st) {
  #pragma unroll
  for (int rep = 0; rep < 2; ++rep) {
    const int cid = ct + 256 * rep;
    const int key = cid >> 3, c = cid & 7;
    st.k4[rep] = *(const float4*)(mb + (size_t)(key0 + key) * DIN + KOFF + 4 * c);
  }
  const int ch = ct & 31, h = ct >> 5;
  #pragma unroll
  for (int r = 0; r < 8; ++r)
    st.v[r] = mb[(size_t)(key0 + h * 8 + r) * DIN + VSRC + ch];
}

__device__ __forceinline__ void stage_write(ushort* __restrict__ buf, int ct,
                                            const Stage& st) {
  #pragma unroll
  for (int rep = 0; rep < 2; ++rep) {
    const int cid = ct + 256 * rep;
    const int key = cid >> 3, c = cid & 7;
    const float* kf = (const float*)&st.k4[rep];
    ushort h4[4], l4[4];
    #pragma unroll
    for (int e = 0; e < 4; ++e) {
      const float p  = 2.f * kf[e] - 1.f;       // k' = 2*mem - 1
      const ushort hb = f2b(p);
      h4[e] = hb;
      l4[e] = f2b(p - b2f(hb));
    }
    const int idx = key * 32 + 4 * c;
    *(uint2*)(buf + idx)        = *(const uint2*)h4;
    *(uint2*)(buf + 2048 + idx) = *(const uint2*)l4;
  }
  // V^T: lane holds ch (0..31) x 8 consecutive keys h*8+r. Column for key g
  // (within group): col = 8*((g&31)>>2&3) + 4*((g&31)>>4) + (g&3), sub = g>>5.
  // For a fixed h this is two quads at cb and cb+2 (cb = 4*(h&1) + ((h&3)>>1)).
  const int ch = ct & 31, h = ct >> 5;
  const int sub = h >> 2;
  const int cb  = 4 * (h & 1) + ((h & 3) >> 1);
  ushort v4[8];
  #pragma unroll
  for (int r = 0; r < 8; ++r) v4[r] = f2b(st.v[r]);
  ushort* vbase = buf + 4096 + ch * 72 + sub * 32;   // stride 72 breaks bank aliasing
  *(uint2*)(vbase + cb * 4)       = *(const uint2*)&v4[0];
  *(uint2*)(vbase + (cb + 2) * 4) = *(const uint2*)&v4[4];
}

__global__ __launch_bounds__(BLK)
void attn_mfma(const float* __restrict__ tgt, const float* __restrict__ mem,
               float* __restrict__ out) {
  __shared__ ushort stage[2][2][BUFU];   // 51.2 KB (2 ks x dbuf); merge overlays it
  __shared__ float  olds[4][560];        // per-rg results: [32 ch][17] + delta265[16]

  const int tid  = threadIdx.x;
  const int lane = tid & 63;
  const int wv   = tid >> 6;
  const int rg   = wv & 3;
  const int ks   = wv >> 2;
  const int Q    = lane >> 4;
  const int r15  = lane & 15;
  const int ct   = rg * 64 + lane;       // id within the 4-wave staging cohort

  const int b  = blockIdx.x >> 5;
  const int t0 = (blockIdx.x & 31) * 64;

  const float* mb   = mem + (size_t)b * S_ * DIN;
  const int    key0 = ks * SEG;

  Stage st;
  stage_issue(mb, key0, ct, st);

  // P fragments: element j of lane = p[row=r15][i = 8Q+j], hi/lo bf16 split.
  const float* trow = tgt + (size_t)(b * T_ + t0 + rg * 16 + r15) * DIN + QOFF + 8 * Q;
  float4 qa = *(const float4*)trow;
  float4 qb = *(const float4*)(trow + 4);
  bf16x8 phi, plo;
  {
    const float pv[8] = {qa.x, qa.y, qa.z, qa.w, qb.x, qb.y, qb.z, qb.w};
    #pragma unroll
    for (int e = 0; e < 8; ++e) {
      const float p  = 2.f * pv[e] - 1.f;
      const ushort hb = f2b(p);
      phi[e] = (short)hb;
      plo[e] = (short)f2b(p - b2f(hb));
    }
  }

  float m  = 31.f;                               // fixed token score (exact)
  float ls = (Q == 0 && ks == 0) ? 1.f : 0.f;    // its exp, seeded once
  f32x4 oc0 = {0.f, 0.f, 0.f, 0.f}, oc1 = {0.f, 0.f, 0.f, 0.f};

  stage_write(&stage[ks][0][0], ct, st);
  __syncthreads();

  for (int g = 0; g < NG; ++g) {
    if (g + 1 < NG) stage_issue(mb, key0 + (g + 1) * GK, ct, st);  // T14: issue early
    const ushort* buf = &stage[ks][g & 1][0];

    // ---- scores: 4 tiles x 16 keys; C[key][row], row = r15
    f32x4 c4[4];
    #pragma unroll
    for (int mt = 0; mt < 4; ++mt) {
      const bf16x8 khi = *(const bf16x8*)(buf + (mt * 16 + r15) * 32 + 8 * Q);
      const bf16x8 klo = *(const bf16x8*)(buf + 2048 + (mt * 16 + r15) * 32 + 8 * Q);
      f32x4 z = {0.f, 0.f, 0.f, 0.f};
      z = __builtin_amdgcn_mfma_f32_16x16x32_bf16(khi, phi, z, 0, 0, 0);
      z = __builtin_amdgcn_mfma_f32_16x16x32_bf16(khi, plo, z, 0, 0, 0);
      z = __builtin_amdgcn_mfma_f32_16x16x32_bf16(klo, phi, z, 0, 0, 0);
      c4[mt] = z;
    }

    // ---- online softmax (row = r15; keys split over Q-groups and regs)
    float gm = c4[0][0];
    #pragma unroll
    for (int mt = 0; mt < 4; ++mt)
      #pragma unroll
      for (int r = 0; r < 4; ++r) gm = fmaxf(gm, c4[mt][r]);
    gm = fmaxf(gm, __shfl_xor(gm, 16));
    gm = fmaxf(gm, __shfl_xor(gm, 32));
    const float mn  = fmaxf(m, gm);
    const float scl = __expf(m - mn);
    m = mn;
    ls *= scl;
    #pragma unroll
    for (int i = 0; i < 4; ++i) { oc0[i] *= scl; oc1[i] *= scl; }

    bf16x8 wf0, wf1;
    float wsum = 0.f;
    #pragma unroll
    for (int mt = 0; mt < 4; ++mt)
      #pragma unroll
      for (int r = 0; r < 4; ++r) {
        const float w = __expf(c4[mt][r] - mn);
        wsum += w;
        const short wb = (short)f2b(w);
        if (mt < 2) wf0[(mt & 1) * 4 + r] = wb;
        else        wf1[(mt & 1) * 4 + r] = wb;
      }
    ls += wsum;

    // ---- PV: oc[hh] += V^T(ch-half hh) x W   (C[ch][row])
    #pragma unroll
    for (int sub = 0; sub < 2; ++sub) {
      const bf16x8 wf = (sub == 0) ? wf0 : wf1;
      const bf16x8 vf0 = *(const bf16x8*)(buf + 4096 + r15 * 72        + sub * 32 + 8 * Q);
      const bf16x8 vf1 = *(const bf16x8*)(buf + 4096 + (16 + r15) * 72 + sub * 32 + 8 * Q);
      oc0 = __builtin_amdgcn_mfma_f32_16x16x32_bf16(vf0, wf, oc0, 0, 0, 0);
      oc1 = __builtin_amdgcn_mfma_f32_16x16x32_bf16(vf1, wf, oc1, 0, 0, 0);
    }

    __syncthreads();
    if (g + 1 < NG) stage_write(&stage[ks][(g + 1) & 1][0], ct, st);
    __syncthreads();
  }

  // ---- merge ks=1 into ks=0 (per row, per Q-group), overlay on staging LDS
  float* msl = (float*)&stage[0][0][0];
  if (ks == 1) {
    float* d = msl + rg * 640;
    d[lane] = m;
    d[64 + lane] = ls;
    #pragma unroll
    for (int i = 0; i < 4; ++i) {
      d[128 + i * 64 + lane] = oc0[i];
      d[384 + i * 64 + lane] = oc1[i];
    }
  }
  __syncthreads();
  if (ks == 0) {
    const float* s = msl + rg * 640;
    const float m1 = s[lane], l1 = s[64 + lane];
    const float mn = fmaxf(m, m1);
    const float sa = __expf(m - mn), sb = __expf(m1 - mn);
    ls = ls * sa + l1 * sb;
    #pragma unroll
    for (int i = 0; i < 4; ++i) {
      oc0[i] = oc0[i] * sa + s[128 + i * 64 + lane] * sb;
      oc1[i] = oc1[i] * sa + s[384 + i * 64 + lane] * sb;
    }
    m = mn;
    float t2 = ls + __shfl_xor(ls, 16);       // sum partials across Q-groups
    const float lt  = t2 + __shfl_xor(t2, 32);
    const float inv = 1.f / lt;
    #pragma unroll
    for (int i = 0; i < 4; ++i) {
      olds[rg][(4 * Q + i) * 17 + r15]      = oc0[i] * inv;   // ch 0..15
      olds[rg][(16 + 4 * Q + i) * 17 + r15] = oc1[i] * inv;   // ch 16..31
    }
    if (Q == 0) olds[rg][32 * 17 + r15] = 1.f - __expf(31.f - m) * inv;
  }
  __syncthreads();

  // ---- epilogue: out = tgt + sparse update (ch 200..231 and 265)
  const size_t base = (size_t)(b * T_ + t0) * DIN;
  #pragma unroll
  for (int k = 0; k < 16; ++k) {
    const int vid = tid + BLK * k;          // 64 rows x 128 float4
    const int row = vid >> 7;
    const int c4i = vid & 127;
    const size_t off = base + (size_t)row * DIN + c4i * 4;
    float4 ov = *(const float4*)(tgt + off);
    const int rg2 = row >> 4, rr = row & 15;
    if (c4i >= 50 && c4i < 58) {            // channels 200..231
      const int j = (c4i - 50) * 4;
      ov.x += olds[rg2][(j + 0) * 17 + rr];
      ov.y += olds[rg2][(j + 1) * 17 + rr];
      ov.z += olds[rg2][(j + 2) * 17 + rr];
      ov.w += olds[rg2][(j + 3) * 17 + rr];
    } else if (c4i == 66) {                 // channel 265 is .y of float4 66
      ov.y += olds[rg2][32 * 17 + rr];
    }
    *(float4*)(out + off) = ov;
  }
}

extern "C" void kernel_launch(void* const* d_in, const int* in_sizes, int n_in,
                              void* d_out, int out_size, void* d_ws, size_t ws_size,
                              hipStream_t stream) {
  const float* tgt = (const float*)d_in[0];
  const float* mem = (const float*)d_in[1];
  float* out = (float*)d_out;
  attn_mfma<<<dim3(B_ * (T_ / 64)), dim3(BLK), 0, stream>>>(tgt, mem, out);
}